// Round 9
// baseline (2103.773 us; speedup 1.0000x reference)
//
#include <hip/hip_runtime.h>
#include <hip/hip_fp16.h>
#include <hip/hip_bf16.h>

// ---------------------------------------------------------------------------
// HAConvGNN forward. Round 9: GRU step rebuilt — raw s_barrier (no vmcnt
// drain), natural fragment ownership (conflict-free A write, no xbuf LDS),
// x prefetch in registers, single-buffer A. Weights 5-in-reg + 1-in-LDS.
// ---------------------------------------------------------------------------

typedef __attribute__((ext_vector_type(8))) short  bf16x8;
typedef __attribute__((ext_vector_type(4))) float  f32x4;

__device__ inline unsigned short f2bs(float f) {
  __hip_bfloat16 h = __float2bfloat16(f);
  unsigned short u; __builtin_memcpy(&u, &h, 2); return u;
}
__device__ inline float bs2f(unsigned short u) {
  unsigned v = (unsigned)u << 16;
  float f; __builtin_memcpy(&f, &v, 4); return f;
}
__device__ inline float sigf(float x) { return 1.f / (1.f + __expf(-x)); }
__device__ inline float tanhf_(float x) {
  const float e = __expf(-2.f * fabsf(x));
  return copysignf((1.f - e) / (1.f + e), x);
}

// ---------------- bf16 MFMA GEMM -------------------------------------------
// C[M,N] = A[M,K] * B^T (B stored [N][K]) with batching z=(batch, ksplit).
// ABF/BBF: operand is bf16 in global (else fp32, converted during staging).
// OUTM: 0 = fp32 (+bias/relu), 1 = bf16 (+bias/relu), 2 = fp32 atomicAdd,
//       3 = transposed bf16 (writes C^T[N][M]).
// GATHER: A rows gathered via gidx (fp32 A only).
// BKN: B stored [K][N] (staging transpose; dtype per BBF).
template <bool ABF, bool BBF, int OUTM, bool RELU, bool GATHER = false, bool BKN = false>
__global__ __launch_bounds__(256) void k_mfma(
    const void* __restrict__ Av, long lda, long a_ss, long a_sb,
    const void* __restrict__ Bv, long ldb, long b_ss, long b_sb,
    void* __restrict__ Cv, long ldc, long c_ss, long c_sb,
    const float* __restrict__ bias, long bias_ss,
    const int* __restrict__ gidx,
    int M, int N, int K, int zb, int ksplit)
{
  __shared__ unsigned short As[128][40];  // 32 k + 8 pad
  __shared__ unsigned short Bs[128][40];
  const int tid = threadIdx.x;
  const int zi = blockIdx.z;
  const int bi = zi / ksplit;
  const int ks = zi - bi * ksplit;
  const int sIdx = bi / zb;
  const int bIdx = bi - sIdx * zb;
  const int row0 = blockIdx.y * 128;
  const int col0 = blockIdx.x * 128;
  const int Kc = ((K + ksplit * 32 - 1) / (ksplit * 32)) * 32;
  const int kbeg = ks * Kc;
  const int kend = min(K, kbeg + Kc);
  if (kbeg >= kend) return;

  const char* Ab = (const char*)Av + ((long)sIdx * a_ss + (long)bIdx * a_sb) * (ABF ? 2 : 4);
  const char* Bb = (const char*)Bv + ((long)sIdx * b_ss + (long)bIdx * b_sb) * (BBF ? 2 : 4);
  char* Cb = (char*)Cv + ((long)sIdx * c_ss + (long)bIdx * c_sb) * ((OUTM == 1 || OUTM == 3) ? 2 : 4);

  const int w = tid >> 6, l = tid & 63;
  const int wr = w >> 1, wc = w & 1;
  const int lr = l & 15, lg = l >> 4;

  f32x4 acc[4][4];
#pragma unroll
  for (int m = 0; m < 4; ++m)
#pragma unroll
    for (int n = 0; n < 4; ++n) acc[m][n] = f32x4{0.f, 0.f, 0.f, 0.f};

  const int sr = tid >> 1;          // staged row 0..127
  const int sk = (tid & 1) * 16;    // staged k base

  for (int kt = kbeg; kt < kend; kt += 32) {
    // ---- stage A tile [128 rows][32 k]
    {
      const int gr = row0 + sr;
      if (ABF) {
        const unsigned short* src = (const unsigned short*)(Ab + ((long)gr * lda + kt + sk) * 2);
        if (gr < M && kt + sk + 16 <= kend) {
          const uint2* p = (const uint2*)src;
          *(uint2*)&As[sr][sk + 0]  = p[0];
          *(uint2*)&As[sr][sk + 4]  = p[1];
          *(uint2*)&As[sr][sk + 8]  = p[2];
          *(uint2*)&As[sr][sk + 12] = p[3];
        } else {
#pragma unroll
          for (int i = 0; i < 16; ++i) {
            const int kk = kt + sk + i;
            As[sr][sk + i] = (gr < M && kk < kend) ? src[i] : (unsigned short)0;
          }
        }
      } else {
        const float* src;
        if (GATHER) src = (const float*)Av + ((gr < M) ? (long)gidx[gr] * lda : 0) + kt + sk;
        else        src = (const float*)(Ab + ((long)gr * lda + kt + sk) * 4);
        if (gr < M && kt + sk + 16 <= kend) {
#pragma unroll
          for (int q = 0; q < 4; ++q) {
            const float4 v = ((const float4*)src)[q];
            *(unsigned*)&As[sr][sk + q * 4 + 0] = (unsigned)f2bs(v.x) | ((unsigned)f2bs(v.y) << 16);
            *(unsigned*)&As[sr][sk + q * 4 + 2] = (unsigned)f2bs(v.z) | ((unsigned)f2bs(v.w) << 16);
          }
        } else {
#pragma unroll
          for (int i = 0; i < 16; ++i) {
            const int kk = kt + sk + i;
            As[sr][sk + i] = (gr < M && kk < kend) ? f2bs(src[i]) : (unsigned short)0;
          }
        }
      }
    }
    // ---- stage B tile [128 cols][32 k]
    if (BKN) {
      const int kk = tid >> 3;          // k-local 0..31
      const int cb = (tid & 7) * 16;    // col base
      const int gk = kt + kk;
#pragma unroll
      for (int q = 0; q < 16; ++q) {
        const int gc = col0 + cb + q;
        unsigned short v = 0;
        if (gk < kend && gc < N) {
          if (BBF) v = ((const unsigned short*)Bb)[(long)gk * ldb + gc];
          else     v = f2bs(((const float*)Bb)[(long)gk * ldb + gc]);
        }
        Bs[cb + q][kk] = v;
      }
    } else {
      const int gc = col0 + sr;
      if (BBF) {
        const unsigned short* src = (const unsigned short*)(Bb + ((long)gc * ldb + kt + sk) * 2);
        if (gc < N && kt + sk + 16 <= kend) {
          const uint2* p = (const uint2*)src;
          *(uint2*)&Bs[sr][sk + 0]  = p[0];
          *(uint2*)&Bs[sr][sk + 4]  = p[1];
          *(uint2*)&Bs[sr][sk + 8]  = p[2];
          *(uint2*)&Bs[sr][sk + 12] = p[3];
        } else {
#pragma unroll
          for (int i = 0; i < 16; ++i) {
            const int kk = kt + sk + i;
            Bs[sr][sk + i] = (gc < N && kk < kend) ? src[i] : (unsigned short)0;
          }
        }
      } else {
        const float* src = (const float*)(Bb + ((long)gc * ldb + kt + sk) * 4);
        if (gc < N && kt + sk + 16 <= kend) {
#pragma unroll
          for (int q = 0; q < 4; ++q) {
            const float4 v = ((const float4*)src)[q];
            *(unsigned*)&Bs[sr][sk + q * 4 + 0] = (unsigned)f2bs(v.x) | ((unsigned)f2bs(v.y) << 16);
            *(unsigned*)&Bs[sr][sk + q * 4 + 2] = (unsigned)f2bs(v.z) | ((unsigned)f2bs(v.w) << 16);
          }
        } else {
#pragma unroll
          for (int i = 0; i < 16; ++i) {
            const int kk = kt + sk + i;
            Bs[sr][sk + i] = (gc < N && kk < kend) ? f2bs(src[i]) : (unsigned short)0;
          }
        }
      }
    }
    __syncthreads();
    // ---- compute
    bf16x8 af[4], bf[4];
#pragma unroll
    for (int m = 0; m < 4; ++m)
      af[m] = *(const bf16x8*)&As[wr * 64 + m * 16 + lr][lg * 8];
#pragma unroll
    for (int n = 0; n < 4; ++n)
      bf[n] = *(const bf16x8*)&Bs[wc * 64 + n * 16 + lr][lg * 8];
#pragma unroll
    for (int m = 0; m < 4; ++m)
#pragma unroll
      for (int n = 0; n < 4; ++n)
        acc[m][n] = __builtin_amdgcn_mfma_f32_16x16x32_bf16(af[m], bf[n], acc[m][n], 0, 0, 0);
    __syncthreads();
  }

  // ---- epilogue
  const float* bp = bias ? bias + (long)sIdx * bias_ss : nullptr;
#pragma unroll
  for (int m = 0; m < 4; ++m) {
#pragma unroll
    for (int n = 0; n < 4; ++n) {
      const int col = col0 + wc * 64 + n * 16 + lr;
      const int rb  = row0 + wr * 64 + m * 16 + lg * 4;
      const f32x4 v = acc[m][n];
      if (col >= N) continue;
      if (OUTM == 3) {
        unsigned short* ct = (unsigned short*)Cb + (long)col * ldc + rb;
        if (rb + 4 <= M) {
          ushort4 pk;
          pk.x = f2bs(v[0]); pk.y = f2bs(v[1]); pk.z = f2bs(v[2]); pk.w = f2bs(v[3]);
          *(ushort4*)ct = pk;
        } else {
#pragma unroll
          for (int r = 0; r < 4; ++r) if (rb + r < M) ct[r] = f2bs(v[r]);
        }
      } else {
        const float bv = bp ? bp[col] : 0.f;
#pragma unroll
        for (int r = 0; r < 4; ++r) {
          const int row = rb + r;
          if (row >= M) continue;
          float x = v[r] + bv;
          if (RELU) x = fmaxf(x, 0.f);
          if (OUTM == 0) ((float*)Cb)[(long)row * ldc + col] = x;
          else if (OUTM == 1) ((unsigned short*)Cb)[(long)row * ldc + col] = f2bs(x);
          else atomicAdd((float*)Cb + (long)row * ldc + col, x);
        }
      }
    }
  }
}

// ---------------- MFMA GRU recurrence v6, CPB chains / block ----------------
// 512 threads = 8 waves. Ownership: thread tid owns the A fragment at
// (kt = tid>>6, lane = tid&63) => chain cO = lane&15, units u0 = kt*32 +
// (lane>>4)*8 .. +7. Activation writes A_lds[tid] (linear, conflict-free).
// x prefetched into registers (no LDS); raw s_barrier + lgkmcnt(0) only so
// the x loads stay in flight across barriers. Weights: n-tiles 0..4 in regs
// (160 VGPR), tile 5 in LDS.
template <int CPB, bool YBF>
__global__ __launch_bounds__(512, 2)
void k_gru_v6(
    const unsigned short* __restrict__ xg,    // [chains][T][768] bf16 (incl bih)
    const float* __restrict__ h0, int h0_mod, // null -> zeros
    const unsigned short* __restrict__ whh_bf, long w_stride, int cpw,
    const float* __restrict__ bhh, long b_stride,
    void* __restrict__ ys, float* __restrict__ hT, int T)
{
  const int tid = threadIdx.x;
  const int c0  = blockIdx.x * CPB;
  const int wv  = tid >> 6;
  const int l   = tid & 63;
  const int lr  = l & 15;
  const int lg  = l >> 4;

  __shared__ unsigned short A_lds[512][8];       // 8 KB; frag idx = tid
  __shared__ unsigned short w_lds[8][8][64][8];  // 64 KB; n-tile 5 per wave
  __shared__ float gate_lds[CPB][772];
  __shared__ float bhh_lds[768];

  // weight fragments: n-tiles 0..4 in registers, tile 5 in LDS
  const unsigned short* W = whh_bf + (long)(c0 / cpw) * w_stride;
  bf16x8 bfr[5][8];
#pragma unroll
  for (int nt = 0; nt < 5; ++nt) {
    const unsigned short* wp = W + (long)(wv * 96 + nt * 16 + lr) * 256 + lg * 8;
#pragma unroll
    for (int kt = 0; kt < 8; ++kt) bfr[nt][kt] = *(const bf16x8*)(wp + kt * 32);
  }
  {
    const unsigned short* wp = W + (long)(wv * 96 + 80 + lr) * 256 + lg * 8;
#pragma unroll
    for (int kt = 0; kt < 8; ++kt)
      *(bf16x8*)&w_lds[wv][kt][l][0] = *(const bf16x8*)(wp + kt * 32);
  }
  for (int i = tid; i < 768; i += 512)
    bhh_lds[i] = bhh[(long)(c0 / cpw) * b_stride + i];

  const bool act = lr < CPB;
  const int cO  = lr;
  const int u0  = wv * 32 + lg * 8;

  // h init + initial A fragment (non-act slots zeroed)
  float h[8];
  {
    bf16x8 pk;
#pragma unroll
    for (int e = 0; e < 8; ++e) {
      float hv = 0.f;
      if (act && h0) hv = h0[(long)((c0 + cO) % h0_mod) * 256 + u0 + e];
      h[e] = hv;
      pk[e] = (short)f2bs(hv);
    }
    *(bf16x8*)&A_lds[tid][0] = pk;
  }

  // x prefetch (registers only)
  const unsigned short* xrow = xg + (long)(c0 + cO) * T * 768 + u0;
  bf16x8 xv0, xv1, xv2;
  if (act) {
    xv0 = *(const bf16x8*)(xrow);
    xv1 = *(const bf16x8*)(xrow + 256);
    xv2 = *(const bf16x8*)(xrow + 512);
  }
  __syncthreads();

  for (int t = 0; t < T; ++t) {
    // ---- MFMA phase: gates[CPB x 768] = h_bf @ W^T
    f32x4 acc[6];
#pragma unroll
    for (int nt = 0; nt < 6; ++nt) acc[nt] = f32x4{0.f, 0.f, 0.f, 0.f};
#pragma unroll
    for (int kt = 0; kt < 8; ++kt) {
      const bf16x8 af = *(const bf16x8*)&A_lds[kt * 64 + l][0];
#pragma unroll
      for (int nt = 0; nt < 5; ++nt)
        acc[nt] = __builtin_amdgcn_mfma_f32_16x16x32_bf16(af, bfr[nt][kt], acc[nt], 0, 0, 0);
      const bf16x8 wf = *(const bf16x8*)&w_lds[wv][kt][l][0];
      acc[5] = __builtin_amdgcn_mfma_f32_16x16x32_bf16(af, wf, acc[5], 0, 0, 0);
    }
    if (lg * 4 < CPB) {
#pragma unroll
      for (int nt = 0; nt < 6; ++nt) {
        const int col = wv * 96 + nt * 16 + lr;
#pragma unroll
        for (int r = 0; r < 4; ++r) gate_lds[lg * 4 + r][col] = acc[nt][r];
      }
    }
    asm volatile("s_waitcnt lgkmcnt(0)" ::: "memory");
    __builtin_amdgcn_sched_barrier(0);
    __builtin_amdgcn_s_barrier();
    __builtin_amdgcn_sched_barrier(0);

    // ---- activation phase (compiler inserts counted vmcnt before xv use)
    if (act) {
      float xr[8], xz[8], xn[8];
#pragma unroll
      for (int e = 0; e < 8; ++e) {
        xr[e] = bs2f((unsigned short)xv0[e]);
        xz[e] = bs2f((unsigned short)xv1[e]);
        xn[e] = bs2f((unsigned short)xv2[e]);
      }
      bf16x8 pk;
#pragma unroll
      for (int e = 0; e < 8; ++e) {
        const int u = u0 + e;
        const float rr = sigf(xr[e] + gate_lds[cO][u] + bhh_lds[u]);
        const float zz = sigf(xz[e] + gate_lds[cO][256 + u] + bhh_lds[256 + u]);
        const float nv = tanhf_(xn[e] + rr * (gate_lds[cO][512 + u] + bhh_lds[512 + u]));
        h[e] = (1.f - zz) * nv + zz * h[e];
        pk[e] = (short)f2bs(h[e]);
      }
      *(bf16x8*)&A_lds[tid][0] = pk;
      if (YBF) {
        *(bf16x8*)((unsigned short*)ys + ((long)(c0 + cO) * T + t) * 256 + u0) = pk;
      } else {
        float* yp = (float*)ys + ((long)(c0 + cO) * T + t) * 256 + u0;
        *(float4*)yp = float4{h[0], h[1], h[2], h[3]};
        *(float4*)(yp + 4) = float4{h[4], h[5], h[6], h[7]};
      }
      if (t + 1 < T) {
        const unsigned short* xp = xrow + (long)(t + 1) * 768;
        xv0 = *(const bf16x8*)(xp);
        xv1 = *(const bf16x8*)(xp + 256);
        xv2 = *(const bf16x8*)(xp + 512);
      }
    }
    asm volatile("s_waitcnt lgkmcnt(0)" ::: "memory");
    __builtin_amdgcn_sched_barrier(0);
    __builtin_amdgcn_s_barrier();
    __builtin_amdgcn_sched_barrier(0);
  }
  if (act && hT) {
    float* hp = hT + (long)(c0 + cO) * 256 + u0;
    *(float4*)hp = float4{h[0], h[1], h[2], h[3]};
    *(float4*)(hp + 4) = float4{h[4], h[5], h[6], h[7]};
  }
}

// ---------------- C[M,N] = bias[N] ------------------------------------------
__global__ __launch_bounds__(256) void k_init_bias(
    float* __restrict__ C, const float* __restrict__ bias, int M, int N)
{
  const int total = M * N;
  for (int i = blockIdx.x * 256 + threadIdx.x; i < total; i += gridDim.x * 256)
    C[i] = bias[i % N];
}

// ---------------- astwork_bf[s][b][n][d] = bf16(emb_ast[x2[b][s][n]][d]) ----
__global__ __launch_bounds__(256) void k_gather_ast(
    const float* __restrict__ emb, const int* __restrict__ x2,
    unsigned short* __restrict__ outp)
{
  const int total = 4 * 32 * 300 * 300;
  for (int idx = blockIdx.x * 256 + threadIdx.x; idx < total; idx += gridDim.x * 256) {
    const int d = idx % 300;
    const int r = idx / 300;
    const int n = r % 300;
    const int r2 = r / 300;
    const int b = r2 % 32;
    const int s = r2 / 32;
    outp[idx] = f2bs(emb[(long)x2[(b * 4 + s) * 300 + n] * 300 + d]);
  }
}

// ---------------- oT[c][r] = bf16(w[r][c]) ----------------------------------
__global__ __launch_bounds__(256) void k_twb(
    const float* __restrict__ w, unsigned short* __restrict__ o, int R, int C)
{
  const int total = R * C;
  for (int i = blockIdx.x * 256 + threadIdx.x; i < total; i += gridDim.x * 256) {
    const int r = i / C, c = i - r * C;
    o[(long)c * R + r] = f2bs(w[i]);
  }
}

// ---------------- fp32 -> bf16 copy ----------------------------------------
__global__ __launch_bounds__(256) void k_f2b(
    const float* __restrict__ a, unsigned short* __restrict__ o, int n)
{
  for (int i = blockIdx.x * 256 + threadIdx.x; i < n; i += gridDim.x * 256)
    o[i] = f2bs(a[i]);
}

// ---------------- dot-product attention ------------------------------------
__global__ __launch_bounds__(256) void k_attn(
    const float* __restrict__ q, const float* __restrict__ kv,
    float* __restrict__ out, int Q, int L)
{
  const int bq = blockIdx.x;
  const int b = bq / Q;
  const int tid = threadIdx.x;
  const int g = tid >> 3, l = tid & 7;
  __shared__ float qv[256];
  __shared__ float sc[64];
  qv[tid] = q[(long)bq * 256 + tid];
  __syncthreads();
  for (int k0 = 0; k0 < L; k0 += 32) {
    const int k = k0 + g;
    float s = 0.f;
    if (k < L) {
      const float* kr = kv + ((long)b * L + k) * 256;
      for (int d = l; d < 256; d += 8) s += qv[d] * kr[d];
    }
    s += __shfl_xor(s, 1);
    s += __shfl_xor(s, 2);
    s += __shfl_xor(s, 4);
    if (k < L && l == 0) sc[k] = s * 0.0625f;
  }
  __syncthreads();
  float m = -1e30f;
  for (int k = 0; k < L; ++k) m = fmaxf(m, sc[k]);
  float den = 0.f;
  for (int k = 0; k < L; ++k) den += __expf(sc[k] - m);
  __syncthreads();
  if (tid < L) sc[tid] = __expf(sc[tid] - m);
  __syncthreads();
  const float* kb = kv + (long)b * L * 256;
  float acc = 0.f;
  for (int k = 0; k < L; ++k) acc += sc[k] * kb[(long)k * 256 + tid];
  out[(long)bq * 256 + tid] = acc / den;
}

// ---------------- hierarchy attention weights ------------------------------
__global__ __launch_bounds__(64) void k_hier(
    const float* __restrict__ dec, const float* __restrict__ g4out,
    float* __restrict__ ahier, int Q)
{
  const int bq = blockIdx.x;
  const int b = bq / Q;
  const int l = threadIdx.x;
  float s[4] = {0.f, 0.f, 0.f, 0.f};
#pragma unroll
  for (int i = 0; i < 4; ++i) {
    const int d = l * 4 + i;
    const float qd = dec[(long)bq * 256 + d];
#pragma unroll
    for (int sg = 0; sg < 4; ++sg)
      s[sg] += qd * g4out[((long)sg * 32 + b) * 256 + d];
  }
#pragma unroll
  for (int off = 32; off >= 1; off >>= 1)
#pragma unroll
    for (int sg = 0; sg < 4; ++sg) s[sg] += __shfl_xor(s[sg], off);
  if (l == 0) {
    float m = -1e30f;
#pragma unroll
    for (int sg = 0; sg < 4; ++sg) m = fmaxf(m, s[sg] * 0.0625f);
    float e[4], den = 0.f;
#pragma unroll
    for (int sg = 0; sg < 4; ++sg) { e[sg] = __expf(s[sg] * 0.0625f - m); den += e[sg]; }
#pragma unroll
    for (int sg = 0; sg < 4; ++sg) ahier[(long)bq * 4 + sg] = e[sg] / den;
  }
}

// ---------------- row softmax * hierarchy weight ---------------------------
__global__ __launch_bounds__(64) void k_smax(
    float* __restrict__ sc, const float* __restrict__ ahier)
{
  const int id = blockIdx.x;          // s*960 + (b*30+q)
  const int s = id / 960;
  const int bq = id - s * 960;
  float* row = sc + (long)id * 300;
  const int l = threadIdx.x;
  float v[5];
  float m = -1e30f;
#pragma unroll
  for (int i = 0; i < 5; ++i) {
    const int k = l + i * 64;
    v[i] = (k < 300) ? row[k] * 0.0625f : -1e30f;
    m = fmaxf(m, v[i]);
  }
#pragma unroll
  for (int off = 32; off >= 1; off >>= 1) m = fmaxf(m, __shfl_xor(m, off));
  float den = 0.f;
#pragma unroll
  for (int i = 0; i < 5; ++i) { v[i] = __expf(v[i] - m); den += v[i]; }
#pragma unroll
  for (int off = 32; off >= 1; off >>= 1) den += __shfl_xor(den, off);
  const float w = ahier[(long)bq * 4 + s] / den;
#pragma unroll
  for (int i = 0; i < 5; ++i) {
    const int k = l + i * 64;
    if (k < 300) row[k] = v[i] * w;
  }
}

// ---------------- concat [tctx | dec | actx] -> [960][768] ------------------
__global__ __launch_bounds__(256) void k_concat(
    const float* __restrict__ a, const float* __restrict__ b,
    const float* __restrict__ c, float* __restrict__ out, int rows)
{
  const int total = rows * 768;
  for (int i = blockIdx.x * 256 + threadIdx.x; i < total; i += gridDim.x * 256) {
    const int r = i / 768, col = i - r * 768;
    float v;
    if (col < 256) v = a[(long)r * 256 + col];
    else if (col < 512) v = b[(long)r * 256 + col - 256];
    else v = c[(long)r * 256 + col - 512];
    out[i] = v;
  }
}

// ---------------------------------------------------------------------------
extern "C" void kernel_launch(void* const* d_in, const int* in_sizes, int n_in,
                              void* d_out, int out_size, void* d_ws, size_t ws_size,
                              hipStream_t stream) {
  const int*   x0      = (const int*)d_in[0];
  const int*   x1      = (const int*)d_in[1];
  const int*   x2      = (const int*)d_in[2];
  const float* adj     = (const float*)d_in[3];
  const float* emb_ast = (const float*)d_in[4];
  const float* emb_com = (const float*)d_in[5];
  const float* g1_wih  = (const float*)d_in[6];
  const float* g1_whh  = (const float*)d_in[7];
  const float* g1_bih  = (const float*)d_in[8];
  const float* g1_bhh  = (const float*)d_in[9];
  const float* g2_wih  = (const float*)d_in[10];
  const float* g2_whh  = (const float*)d_in[11];
  const float* g2_bih  = (const float*)d_in[12];
  const float* g2_bhh  = (const float*)d_in[13];
  const float* g4_wih  = (const float*)d_in[14];
  const float* g4_whh  = (const float*)d_in[15];
  const float* g4_bih  = (const float*)d_in[16];
  const float* g4_bhh  = (const float*)d_in[17];
  const float* g58_wih = (const float*)d_in[18];
  const float* g58_whh = (const float*)d_in[19];
  const float* g58_bih = (const float*)d_in[20];
  const float* g58_bhh = (const float*)d_in[21];
  const float* gcn_w   = (const float*)d_in[22];
  const float* gcn_b   = (const float*)d_in[23];
  const float* dw      = (const float*)d_in[24];
  const float* db      = (const float*)d_in[25];
  const float* lw      = (const float*)d_in[26];
  const float* lb      = (const float*)d_in[27];
  float* out = (float*)d_out;
  float* ws  = (float*)d_ws;

  // workspace layout (float offsets; bf16 buffers use half the floats)
  unsigned short* astwork_bf = (unsigned short*)ws;                 // [4][32][300][300]
  unsigned short* supportT   = (unsigned short*)(ws + 5760000L);    // [4][32][300][300] transposed
  unsigned short* g58xg_bf   = (unsigned short*)(ws + 11520000L);   // [4][32][300][768]
  unsigned short* outsb_bf   = (unsigned short*)(ws + 26265600L);   // [4][32][300][256]
  unsigned short* xg1_bf     = (unsigned short*)(ws + 31180800L);   // [32][50][768]
  unsigned short* xg2_bf     = (unsigned short*)(ws + 31795200L);   // [32][30][768]
  float* tenc    = ws + 32163840L;  // [32][50][256]
  float* tstate  = ws + 32573440L;  // [32][256]
  float* dec     = ws + 32581632L;  // [32][30][256]
  float* tctx    = ws + 32827392L;  // [32][30][256]
  float* g4xg    = ws + 33073152L;  // [4][32][768] fp32 (atomic)
  float* g4out   = ws + 33171456L;  // [4][32][256]
  float* ahier   = ws + 33204224L;  // [32][30][4]
  float* actx1   = ws + 33208064L;  // [32][30][256]
  float* actx    = ws + 33453824L;  // [32][30][256]
  float* dense   = ws + 33699584L;  // [32][30][256]
  float* ctmp    = ws + 33945344L;  // [960][768]
  float* scbuf   = ws + 34682624L;  // [4][32][30][300]
  unsigned short* gcn_wT    = (unsigned short*)(ws + 35834624L);    // [300][300]
  unsigned short* dense_bf  = (unsigned short*)(ws + 35879624L);    // [960][256]
  unsigned short* g1whh_bf  = (unsigned short*)(ws + 36002504L);    // [768][256]
  unsigned short* g2whh_bf  = (unsigned short*)(ws + 36100808L);
  unsigned short* g4whh_bf  = (unsigned short*)(ws + 36199112L);
  unsigned short* g58whh_bf = (unsigned short*)(ws + 36297416L);    // [4][768][256]
  unsigned short* adj_bf    = (unsigned short*)(ws + 36690632L);    // [32][4][300][300]
  unsigned short* g4xg_bf   = (unsigned short*)(ws + 42450632L);    // [4][32][768]

  const dim3 blk(256);

  // 0) weight preps
  k_gather_ast<<<dim3(4096), blk, 0, stream>>>(emb_ast, x2, astwork_bf);
  k_twb<<<dim3(90), blk, 0, stream>>>(gcn_w, gcn_wT, 300, 300);
  k_f2b<<<dim3(192), blk, 0, stream>>>(g1_whh, g1whh_bf, 196608);
  k_f2b<<<dim3(192), blk, 0, stream>>>(g2_whh, g2whh_bf, 196608);
  k_f2b<<<dim3(192), blk, 0, stream>>>(g4_whh, g4whh_bf, 196608);
  k_f2b<<<dim3(768), blk, 0, stream>>>(g58_whh, g58whh_bf, 786432);
  k_f2b<<<dim3(4096), blk, 0, stream>>>(adj, adj_bf, 11520000);

  // 2) GCN, 2 hops (MFMA): supportT = (X @ W)^T ; X = relu(adj @ support + b)
  for (int hop = 0; hop < 2; ++hop) {
    k_mfma<true, true, 3, false><<<dim3(3, 3, 128), blk, 0, stream>>>(
        astwork_bf, 300, 2880000, 90000,
        gcn_wT, 300, 0, 0,
        supportT, 300, 2880000, 90000,
        nullptr, 0, nullptr, 300, 300, 300, 32, 1);
    k_mfma<true, true, 1, true><<<dim3(3, 3, 128), blk, 0, stream>>>(
        adj_bf, 300, 90000, 360000,
        supportT, 300, 2880000, 90000,
        astwork_bf, 300, 2880000, 90000,
        gcn_b, 0, nullptr, 300, 300, 300, 32, 1);
  }

  // 3) token encoder GRU1 (bf16 x-gates) + recurrence
  k_mfma<false, false, 1, false, true><<<dim3(6, 13, 1), blk, 0, stream>>>(
      emb_ast, 300, 0, 0, g1_wih, 300, 0, 0, xg1_bf, 768, 0, 0,
      g1_bih, 0, x0, 1600, 768, 300, 1, 1);
  k_gru_v6<8, false><<<dim3(4), dim3(512), 0, stream>>>(
      xg1_bf, nullptr, 1, g1whh_bf, 0, 32, g1_bhh, 0, tenc, tstate, 50);

  // 4) comment decoder GRU2
  k_mfma<false, false, 1, false, true><<<dim3(6, 8, 1), blk, 0, stream>>>(
      emb_com, 300, 0, 0, g2_wih, 300, 0, 0, xg2_bf, 768, 0, 0,
      g2_bih, 0, x1, 960, 768, 300, 1, 1);
  k_gru_v6<8, false><<<dim3(4), dim3(512), 0, stream>>>(
      xg2_bf, tstate, 32, g2whh_bf, 0, 32, g2_bhh, 0, dec, nullptr, 30);

  // 5) tcontext = dot_attn(dec, tenc)
  k_attn<<<dim3(960), blk, 0, stream>>>(dec, tenc, tctx, 30, 50);

  // 6) gru4: input gates via MFMA split-K atomic (fp32), bf16 copy, recurrence
  k_init_bias<<<dim3(384), blk, 0, stream>>>(g4xg, g4_bih, 128, 768);
  k_mfma<true, false, 2, false><<<dim3(6, 1, 43), blk, 0, stream>>>(
      astwork_bf, 90000, 0, 0, g4_wih, 90000, 0, 0, g4xg, 768, 0, 0,
      nullptr, 0, nullptr, 128, 768, 90000, 1, 43);
  k_f2b<<<dim3(384), blk, 0, stream>>>(g4xg, g4xg_bf, 98304);
  k_gru_v6<4, false><<<dim3(1), dim3(512), 0, stream>>>(
      g4xg_bf, nullptr, 1, g4whh_bf, 0, 4, g4_bhh, 0, g4out, nullptr, 32);

  // 7) hierarchy attention weights
  k_hier<<<dim3(960), dim3(64), 0, stream>>>(dec, g4out, ahier, 30);

  // 8) gru5..8 input gates (MFMA, bf16 out) + recurrence (ys bf16)
  k_mfma<true, false, 1, false><<<dim3(6, 75, 4), blk, 0, stream>>>(
      astwork_bf, 300, 2880000, 0, g58_wih, 300, 230400, 0,
      g58xg_bf, 768, 7372800, 0, g58_bih, 768, nullptr, 9600, 768, 300, 1, 1);
  k_gru_v6<8, true><<<dim3(16), dim3(512), 0, stream>>>(
      g58xg_bf, tstate, 32, g58whh_bf, 196608, 32, g58_bhh, 768,
      outsb_bf, nullptr, 300);

  // 9) node attention + hierarchical combine (bf16 V)
  k_mfma<false, true, 0, false><<<dim3(3, 1, 128), blk, 0, stream>>>(
      dec, 256, 0, 7680, outsb_bf, 256, 2457600, 76800, scbuf, 300, 288000, 9000,
      nullptr, 0, nullptr, 30, 300, 256, 32, 1);
  k_smax<<<dim3(3840), dim3(64), 0, stream>>>(scbuf, ahier);
  hipMemsetAsync(actx1, 0, 245760 * sizeof(float), stream);
  k_mfma<false, true, 2, false, false, true><<<dim3(2, 1, 128), blk, 0, stream>>>(
      scbuf, 300, 288000, 9000, outsb_bf, 256, 2457600, 76800, actx1, 256, 0, 7680,
      nullptr, 0, nullptr, 30, 256, 300, 32, 1);

  // 10) acontext = dot_attn(dec, actx1)
  k_attn<<<dim3(960), blk, 0, stream>>>(dec, actx1, actx, 30, 30);

  // 11) concat + dense (relu, MFMA) + bf16 copy
  k_concat<<<dim3(2880), blk, 0, stream>>>(tctx, dec, actx, ctmp, 960);
  k_mfma<false, false, 0, true><<<dim3(2, 8, 1), blk, 0, stream>>>(
      ctmp, 768, 0, 0, dw, 768, 0, 0, dense, 256, 0, 0,
      db, 0, nullptr, 960, 256, 768, 1, 1);
  k_f2b<<<dim3(960), blk, 0, stream>>>(dense, dense_bf, 245760);

  // 12) final linear via MFMA split-K (streams lw once)
  k_init_bias<<<dim3(1250), blk, 0, stream>>>(out, lb, 32, 10000);
  k_mfma<true, false, 2, false><<<dim3(79, 1, 6), blk, 0, stream>>>(
      dense_bf, 7680, 0, 0, lw, 7680, 0, 0, out, 10000, 0, 0,
      nullptr, 0, nullptr, 32, 10000, 7680, 1, 6);
}

// Round 10
// 1929.197 us; speedup vs baseline: 1.0905x; 1.0905x over previous
//
#include <hip/hip_runtime.h>
#include <hip/hip_fp16.h>
#include <hip/hip_bf16.h>

// ---------------------------------------------------------------------------
// HAConvGNN forward. Round 10: GRU recurrence back to hfma2 chains, sized to
// the register budget: 1024 thr, 4 lanes/unit -> 96 weight-half2/thread
// (fits 128-VGPR cap, no AGPR round-trips), raw s_barrier (x loads stay in
// flight), fp32->f16 weights loaded directly. Rest identical to round 9.
// ---------------------------------------------------------------------------

typedef __attribute__((ext_vector_type(8))) short  bf16x8;
typedef __attribute__((ext_vector_type(4))) float  f32x4;

__device__ inline unsigned short f2bs(float f) {
  __hip_bfloat16 h = __float2bfloat16(f);
  unsigned short u; __builtin_memcpy(&u, &h, 2); return u;
}
__device__ inline float bs2f(unsigned short u) {
  unsigned v = (unsigned)u << 16;
  float f; __builtin_memcpy(&f, &v, 4); return f;
}
__device__ inline float sigf(float x) { return 1.f / (1.f + __expf(-x)); }
__device__ inline float tanhf_(float x) {
  const float e = __expf(-2.f * fabsf(x));
  return copysignf((1.f - e) / (1.f + e), x);
}

// ---------------- bf16 MFMA GEMM -------------------------------------------
// C[M,N] = A[M,K] * B^T (B stored [N][K]) with batching z=(batch, ksplit).
// ABF/BBF: operand is bf16 in global (else fp32, converted during staging).
// OUTM: 0 = fp32 (+bias/relu), 1 = bf16 (+bias/relu), 2 = fp32 atomicAdd,
//       3 = transposed bf16 (writes C^T[N][M]).
// GATHER: A rows gathered via gidx (fp32 A only).
// BKN: B stored [K][N] (staging transpose; dtype per BBF).
template <bool ABF, bool BBF, int OUTM, bool RELU, bool GATHER = false, bool BKN = false>
__global__ __launch_bounds__(256) void k_mfma(
    const void* __restrict__ Av, long lda, long a_ss, long a_sb,
    const void* __restrict__ Bv, long ldb, long b_ss, long b_sb,
    void* __restrict__ Cv, long ldc, long c_ss, long c_sb,
    const float* __restrict__ bias, long bias_ss,
    const int* __restrict__ gidx,
    int M, int N, int K, int zb, int ksplit)
{
  __shared__ unsigned short As[128][40];  // 32 k + 8 pad
  __shared__ unsigned short Bs[128][40];
  const int tid = threadIdx.x;
  const int zi = blockIdx.z;
  const int bi = zi / ksplit;
  const int ks = zi - bi * ksplit;
  const int sIdx = bi / zb;
  const int bIdx = bi - sIdx * zb;
  const int row0 = blockIdx.y * 128;
  const int col0 = blockIdx.x * 128;
  const int Kc = ((K + ksplit * 32 - 1) / (ksplit * 32)) * 32;
  const int kbeg = ks * Kc;
  const int kend = min(K, kbeg + Kc);
  if (kbeg >= kend) return;

  const char* Ab = (const char*)Av + ((long)sIdx * a_ss + (long)bIdx * a_sb) * (ABF ? 2 : 4);
  const char* Bb = (const char*)Bv + ((long)sIdx * b_ss + (long)bIdx * b_sb) * (BBF ? 2 : 4);
  char* Cb = (char*)Cv + ((long)sIdx * c_ss + (long)bIdx * c_sb) * ((OUTM == 1 || OUTM == 3) ? 2 : 4);

  const int w = tid >> 6, l = tid & 63;
  const int wr = w >> 1, wc = w & 1;
  const int lr = l & 15, lg = l >> 4;

  f32x4 acc[4][4];
#pragma unroll
  for (int m = 0; m < 4; ++m)
#pragma unroll
    for (int n = 0; n < 4; ++n) acc[m][n] = f32x4{0.f, 0.f, 0.f, 0.f};

  const int sr = tid >> 1;          // staged row 0..127
  const int sk = (tid & 1) * 16;    // staged k base

  for (int kt = kbeg; kt < kend; kt += 32) {
    // ---- stage A tile [128 rows][32 k]
    {
      const int gr = row0 + sr;
      if (ABF) {
        const unsigned short* src = (const unsigned short*)(Ab + ((long)gr * lda + kt + sk) * 2);
        if (gr < M && kt + sk + 16 <= kend) {
          const uint2* p = (const uint2*)src;
          *(uint2*)&As[sr][sk + 0]  = p[0];
          *(uint2*)&As[sr][sk + 4]  = p[1];
          *(uint2*)&As[sr][sk + 8]  = p[2];
          *(uint2*)&As[sr][sk + 12] = p[3];
        } else {
#pragma unroll
          for (int i = 0; i < 16; ++i) {
            const int kk = kt + sk + i;
            As[sr][sk + i] = (gr < M && kk < kend) ? src[i] : (unsigned short)0;
          }
        }
      } else {
        const float* src;
        if (GATHER) src = (const float*)Av + ((gr < M) ? (long)gidx[gr] * lda : 0) + kt + sk;
        else        src = (const float*)(Ab + ((long)gr * lda + kt + sk) * 4);
        if (gr < M && kt + sk + 16 <= kend) {
#pragma unroll
          for (int q = 0; q < 4; ++q) {
            const float4 v = ((const float4*)src)[q];
            *(unsigned*)&As[sr][sk + q * 4 + 0] = (unsigned)f2bs(v.x) | ((unsigned)f2bs(v.y) << 16);
            *(unsigned*)&As[sr][sk + q * 4 + 2] = (unsigned)f2bs(v.z) | ((unsigned)f2bs(v.w) << 16);
          }
        } else {
#pragma unroll
          for (int i = 0; i < 16; ++i) {
            const int kk = kt + sk + i;
            As[sr][sk + i] = (gr < M && kk < kend) ? f2bs(src[i]) : (unsigned short)0;
          }
        }
      }
    }
    // ---- stage B tile [128 cols][32 k]
    if (BKN) {
      const int kk = tid >> 3;          // k-local 0..31
      const int cb = (tid & 7) * 16;    // col base
      const int gk = kt + kk;
#pragma unroll
      for (int q = 0; q < 16; ++q) {
        const int gc = col0 + cb + q;
        unsigned short v = 0;
        if (gk < kend && gc < N) {
          if (BBF) v = ((const unsigned short*)Bb)[(long)gk * ldb + gc];
          else     v = f2bs(((const float*)Bb)[(long)gk * ldb + gc]);
        }
        Bs[cb + q][kk] = v;
      }
    } else {
      const int gc = col0 + sr;
      if (BBF) {
        const unsigned short* src = (const unsigned short*)(Bb + ((long)gc * ldb + kt + sk) * 2);
        if (gc < N && kt + sk + 16 <= kend) {
          const uint2* p = (const uint2*)src;
          *(uint2*)&Bs[sr][sk + 0]  = p[0];
          *(uint2*)&Bs[sr][sk + 4]  = p[1];
          *(uint2*)&Bs[sr][sk + 8]  = p[2];
          *(uint2*)&Bs[sr][sk + 12] = p[3];
        } else {
#pragma unroll
          for (int i = 0; i < 16; ++i) {
            const int kk = kt + sk + i;
            Bs[sr][sk + i] = (gc < N && kk < kend) ? src[i] : (unsigned short)0;
          }
        }
      } else {
        const float* src = (const float*)(Bb + ((long)gc * ldb + kt + sk) * 4);
        if (gc < N && kt + sk + 16 <= kend) {
#pragma unroll
          for (int q = 0; q < 4; ++q) {
            const float4 v = ((const float4*)src)[q];
            *(unsigned*)&Bs[sr][sk + q * 4 + 0] = (unsigned)f2bs(v.x) | ((unsigned)f2bs(v.y) << 16);
            *(unsigned*)&Bs[sr][sk + q * 4 + 2] = (unsigned)f2bs(v.z) | ((unsigned)f2bs(v.w) << 16);
          }
        } else {
#pragma unroll
          for (int i = 0; i < 16; ++i) {
            const int kk = kt + sk + i;
            Bs[sr][sk + i] = (gc < N && kk < kend) ? f2bs(src[i]) : (unsigned short)0;
          }
        }
      }
    }
    __syncthreads();
    // ---- compute
    bf16x8 af[4], bf[4];
#pragma unroll
    for (int m = 0; m < 4; ++m)
      af[m] = *(const bf16x8*)&As[wr * 64 + m * 16 + lr][lg * 8];
#pragma unroll
    for (int n = 0; n < 4; ++n)
      bf[n] = *(const bf16x8*)&Bs[wc * 64 + n * 16 + lr][lg * 8];
#pragma unroll
    for (int m = 0; m < 4; ++m)
#pragma unroll
      for (int n = 0; n < 4; ++n)
        acc[m][n] = __builtin_amdgcn_mfma_f32_16x16x32_bf16(af[m], bf[n], acc[m][n], 0, 0, 0);
    __syncthreads();
  }

  // ---- epilogue
  const float* bp = bias ? bias + (long)sIdx * bias_ss : nullptr;
#pragma unroll
  for (int m = 0; m < 4; ++m) {
#pragma unroll
    for (int n = 0; n < 4; ++n) {
      const int col = col0 + wc * 64 + n * 16 + lr;
      const int rb  = row0 + wr * 64 + m * 16 + lg * 4;
      const f32x4 v = acc[m][n];
      if (col >= N) continue;
      if (OUTM == 3) {
        unsigned short* ct = (unsigned short*)Cb + (long)col * ldc + rb;
        if (rb + 4 <= M) {
          ushort4 pk;
          pk.x = f2bs(v[0]); pk.y = f2bs(v[1]); pk.z = f2bs(v[2]); pk.w = f2bs(v[3]);
          *(ushort4*)ct = pk;
        } else {
#pragma unroll
          for (int r = 0; r < 4; ++r) if (rb + r < M) ct[r] = f2bs(v[r]);
        }
      } else {
        const float bv = bp ? bp[col] : 0.f;
#pragma unroll
        for (int r = 0; r < 4; ++r) {
          const int row = rb + r;
          if (row >= M) continue;
          float x = v[r] + bv;
          if (RELU) x = fmaxf(x, 0.f);
          if (OUTM == 0) ((float*)Cb)[(long)row * ldc + col] = x;
          else if (OUTM == 1) ((unsigned short*)Cb)[(long)row * ldc + col] = f2bs(x);
          else atomicAdd((float*)Cb + (long)row * ldc + col, x);
        }
      }
    }
  }
}

// ---------------- GRU recurrence v7: hfma2 chains, 1 chain / block ----------
// 1024 threads = 16 waves. Unit j = tid>>2 (256 units), k-quarter kq = tid&3
// (64 h-elements = 32 half2). Weights: 3 gates x 32 half2 = 96 VGPR/thread,
// converted fp32->f16 at init (fits the 1024-thread 128-VGPR cap; no AGPR).
// Per step: 96 hfma2 dot + f32 flush every 8 + 2-level shfl reduce -> kq==0
// lanes run 1-unit fused activation. Raw s_barrier + lgkmcnt(0) only, so the
// prefetched x stays in flight across barriers (no vmcnt drain).
template <bool YBF>
__global__ __launch_bounds__(1024) void k_gru_v7(
    const unsigned short* __restrict__ xg,    // [chains][T][768] bf16 (incl bih)
    const float* __restrict__ h0, int h0_mod, // null -> zeros
    const float* __restrict__ whh, long w_stride, int cpw,
    const float* __restrict__ bhh, long b_stride,
    void* __restrict__ ys, float* __restrict__ hT, int T)
{
  const int c   = blockIdx.x;
  const int tid = threadIdx.x;
  const int j   = tid >> 2;
  const int kq  = tid & 3;

  __shared__ __half h16[256];

  // weights fp32 -> half2, register-resident
  const float* W = whh + (long)(c / cpw) * w_stride;
  __half2 wr[32], wz[32], wn[32];
  {
    const float* pr = W + (long)j * 256 + kq * 64;
    const float* pz = W + (long)(j + 256) * 256 + kq * 64;
    const float* pn = W + (long)(j + 512) * 256 + kq * 64;
#pragma unroll
    for (int i = 0; i < 32; ++i) {
      wr[i] = __floats2half2_rn(pr[2 * i], pr[2 * i + 1]);
      wz[i] = __floats2half2_rn(pz[2 * i], pz[2 * i + 1]);
      wn[i] = __floats2half2_rn(pn[2 * i], pn[2 * i + 1]);
    }
  }

  const bool act = (kq == 0);
  float br = 0.f, bz = 0.f, bn = 0.f, hold = 0.f;
  if (act) {
    const float* Bh = bhh + (long)(c / cpw) * b_stride;
    br = Bh[j]; bz = Bh[256 + j]; bn = Bh[512 + j];
    hold = h0 ? h0[(long)(c % h0_mod) * 256 + j] : 0.f;
    h16[j] = __float2half(hold);
  }
  const unsigned short* xrow = xg + (long)c * T * 768;
  float xr = 0.f, xz = 0.f, xn = 0.f;
  if (act) {
    xr = bs2f(xrow[j]); xz = bs2f(xrow[256 + j]); xn = bs2f(xrow[512 + j]);
  }
  asm volatile("s_waitcnt lgkmcnt(0)" ::: "memory");
  __builtin_amdgcn_sched_barrier(0);
  __builtin_amdgcn_s_barrier();
  __builtin_amdgcn_sched_barrier(0);

  for (int t = 0; t < T; ++t) {
    // prefetch next step's x (hides under the dot; survives raw barriers)
    float nxr = 0.f, nxz = 0.f, nxn = 0.f;
    if (act && t + 1 < T) {
      const unsigned short* xp = xrow + (long)(t + 1) * 768;
      nxr = bs2f(xp[j]); nxz = bs2f(xp[256 + j]); nxn = bs2f(xp[512 + j]);
    }
    // dot: gates[j] over k-quarter kq
    const __half2* hp = (const __half2*)&h16[0] + kq * 32;
    float sr = 0.f, sz = 0.f, sn = 0.f;
#pragma unroll
    for (int i0 = 0; i0 < 32; i0 += 8) {
      __half2 ar = __float2half2_rn(0.f);
      __half2 az = __float2half2_rn(0.f);
      __half2 an = __float2half2_rn(0.f);
#pragma unroll
      for (int i = 0; i < 8; ++i) {
        const __half2 hv = hp[i0 + i];
        ar = __hfma2(wr[i0 + i], hv, ar);
        az = __hfma2(wz[i0 + i], hv, az);
        an = __hfma2(wn[i0 + i], hv, an);
      }
      sr += __low2float(ar) + __high2float(ar);
      sz += __low2float(az) + __high2float(az);
      sn += __low2float(an) + __high2float(an);
    }
    sr += __shfl_xor(sr, 1); sr += __shfl_xor(sr, 2);
    sz += __shfl_xor(sz, 1); sz += __shfl_xor(sz, 2);
    sn += __shfl_xor(sn, 1); sn += __shfl_xor(sn, 2);
    asm volatile("s_waitcnt lgkmcnt(0)" ::: "memory");
    __builtin_amdgcn_sched_barrier(0);
    __builtin_amdgcn_s_barrier();       // all h16 reads complete
    __builtin_amdgcn_sched_barrier(0);

    if (act) {
      const float rr = sigf(xr + sr + br);
      const float zz = sigf(xz + sz + bz);
      const float nv = tanhf_(xn + rr * (sn + bn));
      hold = (1.f - zz) * nv + zz * hold;
      h16[j] = __float2half(hold);
      if (YBF) ((unsigned short*)ys)[((long)c * T + t) * 256 + j] = f2bs(hold);
      else     ((float*)ys)[((long)c * T + t) * 256 + j] = hold;
    }
    xr = nxr; xz = nxz; xn = nxn;
    asm volatile("s_waitcnt lgkmcnt(0)" ::: "memory");
    __builtin_amdgcn_sched_barrier(0);
    __builtin_amdgcn_s_barrier();       // new h visible
    __builtin_amdgcn_sched_barrier(0);
  }
  if (act && hT) hT[(long)c * 256 + j] = hold;
}

// ---------------- C[M,N] = bias[N] ------------------------------------------
__global__ __launch_bounds__(256) void k_init_bias(
    float* __restrict__ C, const float* __restrict__ bias, int M, int N)
{
  const int total = M * N;
  for (int i = blockIdx.x * 256 + threadIdx.x; i < total; i += gridDim.x * 256)
    C[i] = bias[i % N];
}

// ---------------- astwork_bf[s][b][n][d] = bf16(emb_ast[x2[b][s][n]][d]) ----
__global__ __launch_bounds__(256) void k_gather_ast(
    const float* __restrict__ emb, const int* __restrict__ x2,
    unsigned short* __restrict__ outp)
{
  const int total = 4 * 32 * 300 * 300;
  for (int idx = blockIdx.x * 256 + threadIdx.x; idx < total; idx += gridDim.x * 256) {
    const int d = idx % 300;
    const int r = idx / 300;
    const int n = r % 300;
    const int r2 = r / 300;
    const int b = r2 % 32;
    const int s = r2 / 32;
    outp[idx] = f2bs(emb[(long)x2[(b * 4 + s) * 300 + n] * 300 + d]);
  }
}

// ---------------- oT[c][r] = bf16(w[r][c]) ----------------------------------
__global__ __launch_bounds__(256) void k_twb(
    const float* __restrict__ w, unsigned short* __restrict__ o, int R, int C)
{
  const int total = R * C;
  for (int i = blockIdx.x * 256 + threadIdx.x; i < total; i += gridDim.x * 256) {
    const int r = i / C, c = i - r * C;
    o[(long)c * R + r] = f2bs(w[i]);
  }
}

// ---------------- fp32 -> bf16 copy ----------------------------------------
__global__ __launch_bounds__(256) void k_f2b(
    const float* __restrict__ a, unsigned short* __restrict__ o, int n)
{
  for (int i = blockIdx.x * 256 + threadIdx.x; i < n; i += gridDim.x * 256)
    o[i] = f2bs(a[i]);
}

// ---------------- dot-product attention ------------------------------------
__global__ __launch_bounds__(256) void k_attn(
    const float* __restrict__ q, const float* __restrict__ kv,
    float* __restrict__ out, int Q, int L)
{
  const int bq = blockIdx.x;
  const int b = bq / Q;
  const int tid = threadIdx.x;
  const int g = tid >> 3, l = tid & 7;
  __shared__ float qv[256];
  __shared__ float sc[64];
  qv[tid] = q[(long)bq * 256 + tid];
  __syncthreads();
  for (int k0 = 0; k0 < L; k0 += 32) {
    const int k = k0 + g;
    float s = 0.f;
    if (k < L) {
      const float* kr = kv + ((long)b * L + k) * 256;
      for (int d = l; d < 256; d += 8) s += qv[d] * kr[d];
    }
    s += __shfl_xor(s, 1);
    s += __shfl_xor(s, 2);
    s += __shfl_xor(s, 4);
    if (k < L && l == 0) sc[k] = s * 0.0625f;
  }
  __syncthreads();
  float m = -1e30f;
  for (int k = 0; k < L; ++k) m = fmaxf(m, sc[k]);
  float den = 0.f;
  for (int k = 0; k < L; ++k) den += __expf(sc[k] - m);
  __syncthreads();
  if (tid < L) sc[tid] = __expf(sc[tid] - m);
  __syncthreads();
  const float* kb = kv + (long)b * L * 256;
  float acc = 0.f;
  for (int k = 0; k < L; ++k) acc += sc[k] * kb[(long)k * 256 + tid];
  out[(long)bq * 256 + tid] = acc / den;
}

// ---------------- hierarchy attention weights ------------------------------
__global__ __launch_bounds__(64) void k_hier(
    const float* __restrict__ dec, const float* __restrict__ g4out,
    float* __restrict__ ahier, int Q)
{
  const int bq = blockIdx.x;
  const int b = bq / Q;
  const int l = threadIdx.x;
  float s[4] = {0.f, 0.f, 0.f, 0.f};
#pragma unroll
  for (int i = 0; i < 4; ++i) {
    const int d = l * 4 + i;
    const float qd = dec[(long)bq * 256 + d];
#pragma unroll
    for (int sg = 0; sg < 4; ++sg)
      s[sg] += qd * g4out[((long)sg * 32 + b) * 256 + d];
  }
#pragma unroll
  for (int off = 32; off >= 1; off >>= 1)
#pragma unroll
    for (int sg = 0; sg < 4; ++sg) s[sg] += __shfl_xor(s[sg], off);
  if (l == 0) {
    float m = -1e30f;
#pragma unroll
    for (int sg = 0; sg < 4; ++sg) m = fmaxf(m, s[sg] * 0.0625f);
    float e[4], den = 0.f;
#pragma unroll
    for (int sg = 0; sg < 4; ++sg) { e[sg] = __expf(s[sg] * 0.0625f - m); den += e[sg]; }
#pragma unroll
    for (int sg = 0; sg < 4; ++sg) ahier[(long)bq * 4 + sg] = e[sg] / den;
  }
}

// ---------------- row softmax * hierarchy weight ---------------------------
__global__ __launch_bounds__(64) void k_smax(
    float* __restrict__ sc, const float* __restrict__ ahier)
{
  const int id = blockIdx.x;          // s*960 + (b*30+q)
  const int s = id / 960;
  const int bq = id - s * 960;
  float* row = sc + (long)id * 300;
  const int l = threadIdx.x;
  float v[5];
  float m = -1e30f;
#pragma unroll
  for (int i = 0; i < 5; ++i) {
    const int k = l + i * 64;
    v[i] = (k < 300) ? row[k] * 0.0625f : -1e30f;
    m = fmaxf(m, v[i]);
  }
#pragma unroll
  for (int off = 32; off >= 1; off >>= 1) m = fmaxf(m, __shfl_xor(m, off));
  float den = 0.f;
#pragma unroll
  for (int i = 0; i < 5; ++i) { v[i] = __expf(v[i] - m); den += v[i]; }
#pragma unroll
  for (int off = 32; off >= 1; off >>= 1) den += __shfl_xor(den, off);
  const float w = ahier[(long)bq * 4 + s] / den;
#pragma unroll
  for (int i = 0; i < 5; ++i) {
    const int k = l + i * 64;
    if (k < 300) row[k] = v[i] * w;
  }
}

// ---------------- concat [tctx | dec | actx] -> [960][768] ------------------
__global__ __launch_bounds__(256) void k_concat(
    const float* __restrict__ a, const float* __restrict__ b,
    const float* __restrict__ c, float* __restrict__ out, int rows)
{
  const int total = rows * 768;
  for (int i = blockIdx.x * 256 + threadIdx.x; i < total; i += gridDim.x * 256) {
    const int r = i / 768, col = i - r * 768;
    float v;
    if (col < 256) v = a[(long)r * 256 + col];
    else if (col < 512) v = b[(long)r * 256 + col - 256];
    else v = c[(long)r * 256 + col - 512];
    out[i] = v;
  }
}

// ---------------------------------------------------------------------------
extern "C" void kernel_launch(void* const* d_in, const int* in_sizes, int n_in,
                              void* d_out, int out_size, void* d_ws, size_t ws_size,
                              hipStream_t stream) {
  const int*   x0      = (const int*)d_in[0];
  const int*   x1      = (const int*)d_in[1];
  const int*   x2      = (const int*)d_in[2];
  const float* adj     = (const float*)d_in[3];
  const float* emb_ast = (const float*)d_in[4];
  const float* emb_com = (const float*)d_in[5];
  const float* g1_wih  = (const float*)d_in[6];
  const float* g1_whh  = (const float*)d_in[7];
  const float* g1_bih  = (const float*)d_in[8];
  const float* g1_bhh  = (const float*)d_in[9];
  const float* g2_wih  = (const float*)d_in[10];
  const float* g2_whh  = (const float*)d_in[11];
  const float* g2_bih  = (const float*)d_in[12];
  const float* g2_bhh  = (const float*)d_in[13];
  const float* g4_wih  = (const float*)d_in[14];
  const float* g4_whh  = (const float*)d_in[15];
  const float* g4_bih  = (const float*)d_in[16];
  const float* g4_bhh  = (const float*)d_in[17];
  const float* g58_wih = (const float*)d_in[18];
  const float* g58_whh = (const float*)d_in[19];
  const float* g58_bih = (const float*)d_in[20];
  const float* g58_bhh = (const float*)d_in[21];
  const float* gcn_w   = (const float*)d_in[22];
  const float* gcn_b   = (const float*)d_in[23];
  const float* dw      = (const float*)d_in[24];
  const float* db      = (const float*)d_in[25];
  const float* lw      = (const float*)d_in[26];
  const float* lb      = (const float*)d_in[27];
  float* out = (float*)d_out;
  float* ws  = (float*)d_ws;

  // workspace layout (float offsets; bf16 buffers use half the floats)
  unsigned short* astwork_bf = (unsigned short*)ws;                 // [4][32][300][300]
  unsigned short* supportT   = (unsigned short*)(ws + 5760000L);    // [4][32][300][300] transposed
  unsigned short* g58xg_bf   = (unsigned short*)(ws + 11520000L);   // [4][32][300][768]
  unsigned short* outsb_bf   = (unsigned short*)(ws + 26265600L);   // [4][32][300][256]
  unsigned short* xg1_bf     = (unsigned short*)(ws + 31180800L);   // [32][50][768]
  unsigned short* xg2_bf     = (unsigned short*)(ws + 31795200L);   // [32][30][768]
  float* tenc    = ws + 32163840L;  // [32][50][256]
  float* tstate  = ws + 32573440L;  // [32][256]
  float* dec     = ws + 32581632L;  // [32][30][256]
  float* tctx    = ws + 32827392L;  // [32][30][256]
  float* g4xg    = ws + 33073152L;  // [4][32][768] fp32 (atomic)
  float* g4out   = ws + 33171456L;  // [4][32][256]
  float* ahier   = ws + 33204224L;  // [32][30][4]
  float* actx1   = ws + 33208064L;  // [32][30][256]
  float* actx    = ws + 33453824L;  // [32][30][256]
  float* dense   = ws + 33699584L;  // [32][30][256]
  float* ctmp    = ws + 33945344L;  // [960][768]
  float* scbuf   = ws + 34682624L;  // [4][32][30][300]
  unsigned short* gcn_wT    = (unsigned short*)(ws + 35834624L);    // [300][300]
  unsigned short* dense_bf  = (unsigned short*)(ws + 35879624L);    // [960][256]
  unsigned short* adj_bf    = (unsigned short*)(ws + 36690632L);    // [32][4][300][300]
  unsigned short* g4xg_bf   = (unsigned short*)(ws + 42450632L);    // [4][32][768]

  const dim3 blk(256);

  // 0) preps
  k_gather_ast<<<dim3(4096), blk, 0, stream>>>(emb_ast, x2, astwork_bf);
  k_twb<<<dim3(90), blk, 0, stream>>>(gcn_w, gcn_wT, 300, 300);
  k_f2b<<<dim3(4096), blk, 0, stream>>>(adj, adj_bf, 11520000);

  // 2) GCN, 2 hops (MFMA): supportT = (X @ W)^T ; X = relu(adj @ support + b)
  for (int hop = 0; hop < 2; ++hop) {
    k_mfma<true, true, 3, false><<<dim3(3, 3, 128), blk, 0, stream>>>(
        astwork_bf, 300, 2880000, 90000,
        gcn_wT, 300, 0, 0,
        supportT, 300, 2880000, 90000,
        nullptr, 0, nullptr, 300, 300, 300, 32, 1);
    k_mfma<true, true, 1, true><<<dim3(3, 3, 128), blk, 0, stream>>>(
        adj_bf, 300, 90000, 360000,
        supportT, 300, 2880000, 90000,
        astwork_bf, 300, 2880000, 90000,
        gcn_b, 0, nullptr, 300, 300, 300, 32, 1);
  }

  // 3) token encoder GRU1 (bf16 x-gates) + recurrence
  k_mfma<false, false, 1, false, true><<<dim3(6, 13, 1), blk, 0, stream>>>(
      emb_ast, 300, 0, 0, g1_wih, 300, 0, 0, xg1_bf, 768, 0, 0,
      g1_bih, 0, x0, 1600, 768, 300, 1, 1);
  k_gru_v7<false><<<dim3(32), dim3(1024), 0, stream>>>(
      xg1_bf, nullptr, 1, g1_whh, 0, 32, g1_bhh, 0, tenc, tstate, 50);

  // 4) comment decoder GRU2
  k_mfma<false, false, 1, false, true><<<dim3(6, 8, 1), blk, 0, stream>>>(
      emb_com, 300, 0, 0, g2_wih, 300, 0, 0, xg2_bf, 768, 0, 0,
      g2_bih, 0, x1, 960, 768, 300, 1, 1);
  k_gru_v7<false><<<dim3(32), dim3(1024), 0, stream>>>(
      xg2_bf, tstate, 32, g2_whh, 0, 32, g2_bhh, 0, dec, nullptr, 30);

  // 5) tcontext = dot_attn(dec, tenc)
  k_attn<<<dim3(960), blk, 0, stream>>>(dec, tenc, tctx, 30, 50);

  // 6) gru4: input gates via MFMA split-K atomic (fp32), bf16 copy, recurrence
  k_init_bias<<<dim3(384), blk, 0, stream>>>(g4xg, g4_bih, 128, 768);
  k_mfma<true, false, 2, false><<<dim3(6, 1, 43), blk, 0, stream>>>(
      astwork_bf, 90000, 0, 0, g4_wih, 90000, 0, 0, g4xg, 768, 0, 0,
      nullptr, 0, nullptr, 128, 768, 90000, 1, 43);
  k_f2b<<<dim3(384), blk, 0, stream>>>(g4xg, g4xg_bf, 98304);
  k_gru_v7<false><<<dim3(4), dim3(1024), 0, stream>>>(
      g4xg_bf, nullptr, 1, g4_whh, 0, 4, g4_bhh, 0, g4out, nullptr, 32);

  // 7) hierarchy attention weights
  k_hier<<<dim3(960), dim3(64), 0, stream>>>(dec, g4out, ahier, 30);

  // 8) gru5..8 input gates (MFMA, bf16 out) + recurrence (ys bf16)
  k_mfma<true, false, 1, false><<<dim3(6, 75, 4), blk, 0, stream>>>(
      astwork_bf, 300, 2880000, 0, g58_wih, 300, 230400, 0,
      g58xg_bf, 768, 7372800, 0, g58_bih, 768, nullptr, 9600, 768, 300, 1, 1);
  k_gru_v7<true><<<dim3(128), dim3(1024), 0, stream>>>(
      g58xg_bf, tstate, 32, g58_whh, 196608, 32, g58_bhh, 768,
      outsb_bf, nullptr, 300);

  // 9) node attention + hierarchical combine (bf16 V)
  k_mfma<false, true, 0, false><<<dim3(3, 1, 128), blk, 0, stream>>>(
      dec, 256, 0, 7680, outsb_bf, 256, 2457600, 76800, scbuf, 300, 288000, 9000,
      nullptr, 0, nullptr, 30, 300, 256, 32, 1);
  k_smax<<<dim3(3840), dim3(64), 0, stream>>>(scbuf, ahier);
  hipMemsetAsync(actx1, 0, 245760 * sizeof(float), stream);
  k_mfma<false, true, 2, false, false, true><<<dim3(2, 1, 128), blk, 0, stream>>>(
      scbuf, 300, 288000, 9000, outsb_bf, 256, 2457600, 76800, actx1, 256, 0, 7680,
      nullptr, 0, nullptr, 30, 256, 300, 32, 1);

  // 10) acontext = dot_attn(dec, actx1)
  k_attn<<<dim3(960), blk, 0, stream>>>(dec, actx1, actx, 30, 30);

  // 11) concat + dense (relu, MFMA) + bf16 copy
  k_concat<<<dim3(2880), blk, 0, stream>>>(tctx, dec, actx, ctmp, 960);
  k_mfma<false, false, 0, true><<<dim3(2, 8, 1), blk, 0, stream>>>(
      ctmp, 768, 0, 0, dw, 768, 0, 0, dense, 256, 0, 0,
      db, 0, nullptr, 960, 256, 768, 1, 1);
  k_f2b<<<dim3(960), blk, 0, stream>>>(dense, dense_bf, 245760);

  // 12) final linear via MFMA split-K (streams lw once)
  k_init_bias<<<dim3(1250), blk, 0, stream>>>(out, lb, 32, 10000);
  k_mfma<true, false, 2, false><<<dim3(79, 1, 6), blk, 0, stream>>>(
      dense_bf, 7680, 0, 0, lw, 7680, 0, 0, out, 10000, 0, 0,
      nullptr, 0, nullptr, 32, 10000, 7680, 1, 6);
}